// Round 2
// baseline (90.144 us; speedup 1.0000x reference)
//
#include <hip/hip_runtime.h>
#include <hip/hip_bf16.h>
#include <math.h>

// Problem: B=4, L=4096, D=1024, NB=4, TOPK=2
//   logits = x @ gate_w + gate_b          (B,L,4)
//   top-2 mask (keep logits >= 2nd-largest), softmax
//   out = sum_n w[n] * branches[:,:,n,:]  (B,L,D)
//
// Two-kernel split: gate (latency-ish, 64MB) then blend (pure stream, 320MB).
// Decoupling keeps the 320MB phase free of shuffle/exp dependency stalls.

#define DDIM 1024
#define NBR 4

// ---------------- Kernel 1: per-row gating weights -> d_ws ----------------
__global__ __launch_bounds__(256) void gate_kernel(
    const float* __restrict__ x,
    const float* __restrict__ gate_w,
    const float* __restrict__ gate_b,
    float* __restrict__ wout,     // nrows x 4
    int nrows)
{
    const int lane = threadIdx.x & 63;
    const int wave = threadIdx.x >> 6;
    const int waves_per_block = blockDim.x >> 6;
    const int total_waves = gridDim.x * waves_per_block;
    const int wave_id = blockIdx.x * waves_per_block + wave;

    // Lane owns dims d = j*256 + lane*4 + k (j=0..3,k=0..3).
    // gate_w (D,NB) row-major: 4 weights per dim = contiguous float4.
    float4 gw[4][4];
#pragma unroll
    for (int j = 0; j < 4; ++j)
#pragma unroll
        for (int k = 0; k < 4; ++k)
            gw[j][k] = *(const float4*)(gate_w + (size_t)((j * 256 + lane * 4 + k) * NBR));

    const float4 gb = *(const float4*)gate_b;

    for (int row = wave_id; row < nrows; row += total_waves) {
        const float* xr = x + (size_t)row * DDIM;

        float a0 = 0.f, a1 = 0.f, a2 = 0.f, a3 = 0.f;
#pragma unroll
        for (int j = 0; j < 4; ++j) {
            const float4 xv = *(const float4*)(xr + j * 256 + lane * 4);
            const float xs[4] = {xv.x, xv.y, xv.z, xv.w};
#pragma unroll
            for (int k = 0; k < 4; ++k) {
                a0 = fmaf(xs[k], gw[j][k].x, a0);
                a1 = fmaf(xs[k], gw[j][k].y, a1);
                a2 = fmaf(xs[k], gw[j][k].z, a2);
                a3 = fmaf(xs[k], gw[j][k].w, a3);
            }
        }

        // Packed 64-lane reduce of 4 values in 7 shfls (+3 broadcast).
        // fold1 (xor 1): even lanes keep (a0,a1), odd keep (a2,a3)
        const bool keep1 = (lane & 1) == 0;
        float u0 = keep1 ? a0 : a2;
        float u1 = keep1 ? a1 : a3;
        float s0 = keep1 ? a2 : a0;
        float s1 = keep1 ? a3 : a1;
        u0 += __shfl_xor(s0, 1, 64);
        u1 += __shfl_xor(s1, 1, 64);
        // fold2 (xor 2)
        const bool keep2 = (lane & 2) == 0;
        float v = keep2 ? u0 : u1;
        float s = keep2 ? u1 : u0;
        v += __shfl_xor(s, 2, 64);
        // now lane r=lane&3 holds partial sum of logit m(r): m={0,2,1,3}
#pragma unroll
        for (int off = 4; off <= 32; off <<= 1)
            v += __shfl_xor(v, off, 64);
        // broadcast: from lane0's perspective (r=0): v=lg0, xor1->lg2, xor2->lg1, xor3->lg3
        const float t1 = __shfl_xor(v, 1, 64);
        const float t2 = __shfl_xor(v, 2, 64);
        const float t3 = __shfl_xor(v, 3, 64);

        // Only lane 0's mapping is used for the store.
        float lg[NBR] = {v + gb.x, t2 + gb.y, t1 + gb.z, t3 + gb.w};

        // top-2 threshold (keep logits >= 2nd-largest, duplicates kept)
        float m1 = -INFINITY, m2 = -INFINITY;
#pragma unroll
        for (int n = 0; n < NBR; ++n) {
            const float val = lg[n];
            if (val > m1) { m2 = m1; m1 = val; }
            else if (val > m2) { m2 = val; }
        }
        float w[NBR];
        float sum = 0.f;
#pragma unroll
        for (int n = 0; n < NBR; ++n) {
            const float e = (lg[n] >= m2) ? expf(lg[n] - m1) : 0.0f;
            w[n] = e;
            sum += e;
        }
        const float inv = 1.0f / sum;

        if (lane == 0) {
            float4 wv = make_float4(w[0] * inv, w[1] * inv, w[2] * inv, w[3] * inv);
            *(float4*)(wout + (size_t)row * NBR) = wv;
        }
    }
}

// ---------------- Kernel 2: pure-streaming blend ----------------
__global__ __launch_bounds__(256) void blend_kernel(
    const float* __restrict__ branches,
    const float* __restrict__ wrow,    // nrows x 4 (normalized)
    float* __restrict__ out,
    int nrows)
{
    const int lane = threadIdx.x & 63;
    const int wave = threadIdx.x >> 6;
    const int waves_per_block = blockDim.x >> 6;
    const int total_waves = gridDim.x * waves_per_block;
    const int wave_id = blockIdx.x * waves_per_block + wave;

    for (int row = wave_id; row < nrows; row += total_waves) {
        const float4 w = *(const float4*)(wrow + (size_t)row * NBR);  // uniform broadcast
        const float* br = branches + (size_t)row * (NBR * DDIM);
        float* outr = out + (size_t)row * DDIM;
#pragma unroll
        for (int j = 0; j < 4; ++j) {
            const int d = j * 256 + lane * 4;
            const float4 b0 = *(const float4*)(br + 0 * DDIM + d);
            const float4 b1 = *(const float4*)(br + 1 * DDIM + d);
            const float4 b2 = *(const float4*)(br + 2 * DDIM + d);
            const float4 b3 = *(const float4*)(br + 3 * DDIM + d);
            float4 o;
            o.x = w.x * b0.x + w.y * b1.x + w.z * b2.x + w.w * b3.x;
            o.y = w.x * b0.y + w.y * b1.y + w.z * b2.y + w.w * b3.y;
            o.z = w.x * b0.z + w.y * b1.z + w.z * b2.z + w.w * b3.z;
            o.w = w.x * b0.w + w.y * b1.w + w.z * b2.w + w.w * b3.w;
            *(float4*)(outr + d) = o;
        }
    }
}

// ---------------- Fallback: fused single kernel (proven, R0) ----------------
__global__ __launch_bounds__(256) void titan_fused_kernel(
    const float* __restrict__ x,
    const float* __restrict__ branches,
    const float* __restrict__ gate_w,
    const float* __restrict__ gate_b,
    float* __restrict__ out,
    int nrows)
{
    const int lane = threadIdx.x & 63;
    const int wave = threadIdx.x >> 6;
    const int waves_per_block = blockDim.x >> 6;
    const int total_waves = gridDim.x * waves_per_block;
    const int wave_id = blockIdx.x * waves_per_block + wave;

    float4 gw[4][4];
#pragma unroll
    for (int j = 0; j < 4; ++j)
#pragma unroll
        for (int k = 0; k < 4; ++k)
            gw[j][k] = *(const float4*)(gate_w + (size_t)((j * 256 + lane * 4 + k) * NBR));
    const float4 gb = *(const float4*)gate_b;

    for (int row = wave_id; row < nrows; row += total_waves) {
        const float* xr = x + (size_t)row * DDIM;
        float a0 = 0.f, a1 = 0.f, a2 = 0.f, a3 = 0.f;
#pragma unroll
        for (int j = 0; j < 4; ++j) {
            const float4 xv = *(const float4*)(xr + j * 256 + lane * 4);
            const float xs[4] = {xv.x, xv.y, xv.z, xv.w};
#pragma unroll
            for (int k = 0; k < 4; ++k) {
                a0 = fmaf(xs[k], gw[j][k].x, a0);
                a1 = fmaf(xs[k], gw[j][k].y, a1);
                a2 = fmaf(xs[k], gw[j][k].z, a2);
                a3 = fmaf(xs[k], gw[j][k].w, a3);
            }
        }
#pragma unroll
        for (int off = 32; off >= 1; off >>= 1) {
            a0 += __shfl_xor(a0, off, 64);
            a1 += __shfl_xor(a1, off, 64);
            a2 += __shfl_xor(a2, off, 64);
            a3 += __shfl_xor(a3, off, 64);
        }
        float lg[NBR] = {a0 + gb.x, a1 + gb.y, a2 + gb.z, a3 + gb.w};
        float m1 = -INFINITY, m2 = -INFINITY;
#pragma unroll
        for (int n = 0; n < NBR; ++n) {
            const float val = lg[n];
            if (val > m1) { m2 = m1; m1 = val; }
            else if (val > m2) { m2 = val; }
        }
        float w[NBR]; float sum = 0.f;
#pragma unroll
        for (int n = 0; n < NBR; ++n) {
            const float e = (lg[n] >= m2) ? expf(lg[n] - m1) : 0.0f;
            w[n] = e; sum += e;
        }
        const float inv = 1.0f / sum;
#pragma unroll
        for (int n = 0; n < NBR; ++n) w[n] *= inv;

        const float* br = branches + (size_t)row * (NBR * DDIM);
        float* outr = out + (size_t)row * DDIM;
#pragma unroll
        for (int j = 0; j < 4; ++j) {
            const int d = j * 256 + lane * 4;
            const float4 b0 = *(const float4*)(br + 0 * DDIM + d);
            const float4 b1 = *(const float4*)(br + 1 * DDIM + d);
            const float4 b2 = *(const float4*)(br + 2 * DDIM + d);
            const float4 b3 = *(const float4*)(br + 3 * DDIM + d);
            float4 o;
            o.x = w[0] * b0.x + w[1] * b1.x + w[2] * b2.x + w[3] * b3.x;
            o.y = w[0] * b0.y + w[1] * b1.y + w[2] * b2.y + w[3] * b3.y;
            o.z = w[0] * b0.z + w[1] * b1.z + w[2] * b2.z + w[3] * b3.z;
            o.w = w[0] * b0.w + w[1] * b1.w + w[2] * b2.w + w[3] * b3.w;
            *(float4*)(outr + d) = o;
        }
    }
}

extern "C" void kernel_launch(void* const* d_in, const int* in_sizes, int n_in,
                              void* d_out, int out_size, void* d_ws, size_t ws_size,
                              hipStream_t stream) {
    const float* x        = (const float*)d_in[0];
    const float* branches = (const float*)d_in[1];
    const float* gate_w   = (const float*)d_in[2];
    const float* gate_b   = (const float*)d_in[3];
    float* out = (float*)d_out;

    const int nrows = in_sizes[0] / DDIM;  // B*L = 16384
    const size_t need_ws = (size_t)nrows * NBR * sizeof(float);

    if (d_ws != nullptr && ws_size >= need_ws) {
        float* wrow = (float*)d_ws;
        // Kernel 1: one wave per row exactly (4096 blocks x 4 waves).
        const int blocks1 = (nrows + 3) / 4;
        hipLaunchKernelGGL(gate_kernel, dim3(blocks1), dim3(256), 0, stream,
                           x, gate_w, gate_b, wrow, nrows);
        // Kernel 2: one wave per row, pure streaming.
        const int blocks2 = (nrows + 3) / 4;
        hipLaunchKernelGGL(blend_kernel, dim3(blocks2), dim3(256), 0, stream,
                           branches, wrow, out, nrows);
    } else {
        hipLaunchKernelGGL(titan_fused_kernel, dim3(2048), dim3(256), 0, stream,
                           x, branches, gate_w, gate_b, out, nrows);
    }
}

// Round 4
// 67.869 us; speedup vs baseline: 1.3282x; 1.3282x over previous
//
#include <hip/hip_runtime.h>
#include <hip/hip_bf16.h>
#include <math.h>

// Problem: B=4, L=4096, D=1024, NB=4, TOPK=2
//   logits = x @ gate_w + gate_b          (B,L,4)
//   top-2 mask (keep logits >= 2nd-largest), softmax
//   out = sum_n w[n] * branches[:,:,n,:]  (B,L,D)
//
// Fused, one wave per row (grid-stride, 2 rows/wave). All 20 16B loads
// (x + 16 branch vectors) are issued BEFORE the shuffle-reduce chain so
// the HBM pipe stays busy during the serial reduce+exp phase. Streaming
// data uses non-temporal hints (384 MB footprint > 256 MB L3; no reuse).

#define DDIM 1024
#define NBR 4

typedef float f32x4 __attribute__((ext_vector_type(4)));

__global__ __launch_bounds__(256) void titan_fused_kernel(
    const float* __restrict__ x,
    const float* __restrict__ branches,
    const float* __restrict__ gate_w,
    const float* __restrict__ gate_b,
    float* __restrict__ out,
    int nrows)
{
    const int lane = threadIdx.x & 63;
    const int wave = threadIdx.x >> 6;
    const int waves_per_block = blockDim.x >> 6;
    const int total_waves = gridDim.x * waves_per_block;
    const int wave_id = blockIdx.x * waves_per_block + wave;
    const int d0 = lane * 4;

    // Preload gate_w slice (reused across this wave's rows).
    // Lane owns dims d = j*256 + lane*4 + k; gate_w (D,NB) row-major ->
    // the 4 weights of dim d are one contiguous float4.
    f32x4 gw[4][4];
#pragma unroll
    for (int j = 0; j < 4; ++j)
#pragma unroll
        for (int k = 0; k < 4; ++k)
            gw[j][k] = *(const f32x4*)(gate_w + (size_t)((j * 256 + d0 + k) * NBR));
    const f32x4 gb = *(const f32x4*)gate_b;

    for (int row = wave_id; row < nrows; row += total_waves) {
        const float* xr = x + (size_t)row * DDIM;
        const float* br = branches + (size_t)row * (NBR * DDIM);
        float* outr = out + (size_t)row * DDIM;

        // ---- issue ALL loads up front: 4 x-vectors, then 16 branch-vectors ----
        f32x4 xv[4];
#pragma unroll
        for (int j = 0; j < 4; ++j)
            xv[j] = __builtin_nontemporal_load((const f32x4*)(xr + j * 256 + d0));

        f32x4 bb[4][4];  // [j][n]
#pragma unroll
        for (int j = 0; j < 4; ++j)
#pragma unroll
            for (int n = 0; n < NBR; ++n)
                bb[j][n] = __builtin_nontemporal_load(
                    (const f32x4*)(br + n * DDIM + j * 256 + d0));

        // ---- gating matvec (needs only xv; branch loads keep flying) ----
        float a0 = 0.f, a1 = 0.f, a2 = 0.f, a3 = 0.f;
#pragma unroll
        for (int j = 0; j < 4; ++j) {
#pragma unroll
            for (int k = 0; k < 4; ++k) {
                const float xs = xv[j][k];
                a0 = fmaf(xs, gw[j][k].x, a0);
                a1 = fmaf(xs, gw[j][k].y, a1);
                a2 = fmaf(xs, gw[j][k].z, a2);
                a3 = fmaf(xs, gw[j][k].w, a3);
            }
        }

        // ---- 64-lane tree reduce; branch loads still in flight ----
#pragma unroll
        for (int off = 32; off >= 1; off >>= 1) {
            a0 += __shfl_xor(a0, off, 64);
            a1 += __shfl_xor(a1, off, 64);
            a2 += __shfl_xor(a2, off, 64);
            a3 += __shfl_xor(a3, off, 64);
        }

        float lg[NBR] = {a0 + gb.x, a1 + gb.y, a2 + gb.z, a3 + gb.w};

        // top-2 threshold (keep logits >= 2nd-largest; duplicates kept)
        float m1 = -INFINITY, m2 = -INFINITY;
#pragma unroll
        for (int n = 0; n < NBR; ++n) {
            const float v = lg[n];
            if (v > m1) { m2 = m1; m1 = v; }
            else if (v > m2) { m2 = v; }
        }
        float w[NBR]; float sum = 0.f;
#pragma unroll
        for (int n = 0; n < NBR; ++n) {
            const float e = (lg[n] >= m2) ? expf(lg[n] - m1) : 0.0f;
            w[n] = e; sum += e;
        }
        const float inv = 1.0f / sum;
#pragma unroll
        for (int n = 0; n < NBR; ++n) w[n] *= inv;

        // ---- blend: consume the prefetched branch vectors ----
#pragma unroll
        for (int j = 0; j < 4; ++j) {
            f32x4 o;
            o.x = w[0] * bb[j][0].x + w[1] * bb[j][1].x + w[2] * bb[j][2].x + w[3] * bb[j][3].x;
            o.y = w[0] * bb[j][0].y + w[1] * bb[j][1].y + w[2] * bb[j][2].y + w[3] * bb[j][3].y;
            o.z = w[0] * bb[j][0].z + w[1] * bb[j][1].z + w[2] * bb[j][2].z + w[3] * bb[j][3].z;
            o.w = w[0] * bb[j][0].w + w[1] * bb[j][1].w + w[2] * bb[j][2].w + w[3] * bb[j][3].w;
            __builtin_nontemporal_store(o, (f32x4*)(outr + j * 256 + d0));
        }
    }
}

extern "C" void kernel_launch(void* const* d_in, const int* in_sizes, int n_in,
                              void* d_out, int out_size, void* d_ws, size_t ws_size,
                              hipStream_t stream) {
    const float* x        = (const float*)d_in[0];
    const float* branches = (const float*)d_in[1];
    const float* gate_w   = (const float*)d_in[2];
    const float* gate_b   = (const float*)d_in[3];
    float* out = (float*)d_out;

    const int nrows = in_sizes[0] / DDIM;  // B*L = 16384

    const int block = 256;                  // 4 waves/block
    const int grid = 2048;                  // 8192 waves -> 2 rows per wave
    hipLaunchKernelGGL(titan_fused_kernel, dim3(grid), dim3(block), 0, stream,
                       x, branches, gate_w, gate_b, out, nrows);
}